// Round 8
// baseline (396.268 us; speedup 1.0000x reference)
//
#include <hip/hip_runtime.h>
#include <hip/hip_bf16.h>

// ---------------------------------------------------------------------------
// RelativeMultiHeadAttention: B=2, L=2048, D=1024, H=16, d=64, MAX_REL=512
// Inputs fp32 (auto-detected vs bf16). Internals bf16 MFMA + fp32 accum.
//
// v8: v7 + TBAA fix. v5-v7 NaN root cause: scalar `*(unsigned int*)` LDS
// stores followed by scalar `short` loads of the same location (Pp gather)
// carry distinct TBAA tags under -fstrict-aliasing -> LLVM reorders the
// ds_read before the ds_write -> uninit LDS -> NaN. ALL scalar uint LDS
// stores now go through __builtin_memcpy (may-alias, same ds_write_b32).
// GEMMs remain v4-proven VGPR staging (vector uint4/short8 puns are
// may-alias in LLVM and were proven in v4 -> untouched).
// ---------------------------------------------------------------------------

typedef __attribute__((ext_vector_type(8))) short short8;   // 8 x bf16 frag
typedef __attribute__((ext_vector_type(4))) float floatx4;

#define L_SEQ 2048
#define D_MODEL 1024
#define NHEAD 16
#define DH 64
#define BH 32           // B*H
#define MROWS 4096      // B*L

__device__ inline float b2f(short s) {
    unsigned int u = ((unsigned int)(unsigned short)s) << 16;
    float f; __builtin_memcpy(&f, &u, 4); return f;
}
__device__ inline short f2b(float f) {
    unsigned int u; __builtin_memcpy(&u, &f, 4);
    u += 0x7fffu + ((u >> 16) & 1u);   // round-to-nearest-even
    return (short)(u >> 16);
}
// packed f32x2 -> bf16x2 (v_cvt_pk_bf16_f32 on gfx950)
__device__ inline unsigned int pack2(float a, float b) {
    __hip_bfloat162 h = __float22bfloat162_rn(make_float2(a, b));
    unsigned int u; __builtin_memcpy(&u, &h, 4); return u;
}
// alias-safe 4B store into a short-typed LDS array (ds_write_b32)
__device__ inline void st2(short* p, unsigned int v) {
    __builtin_memcpy(p, &v, 4);
}

// ---------------------------------------------------------------------------
// dtype detector: count bf16 inf/nan exponent patterns in first 64K shorts.
// ---------------------------------------------------------------------------
__global__ __launch_bounds__(256) void detect_dtype(
        const unsigned short* __restrict__ q, int* __restrict__ flag) {
    __shared__ int s[256];
    int tid = threadIdx.x, cnt = 0;
    for (int i = tid; i < 65536; i += 256)
        if ((q[i] & 0x7F80u) == 0x7F80u) cnt++;
    s[tid] = cnt; __syncthreads();
    for (int st = 128; st; st >>= 1) {
        if (tid < st) s[tid] += s[tid + st];
        __syncthreads();
    }
    if (tid == 0) *flag = (s[0] > 4) ? 1 : 0;   // 1 = inputs are fp32
}

// ---------------------------------------------------------------------------
// Canonicalize small tensors: 4 biases -> fp32[4096], rel_emb -> bf16[65600]
// ---------------------------------------------------------------------------
__global__ __launch_bounds__(256) void norm_small(
        const void* __restrict__ bq, const void* __restrict__ bk,
        const void* __restrict__ bv, const void* __restrict__ bo,
        const void* __restrict__ rel, float* __restrict__ bias4,
        short* __restrict__ relb, const int* __restrict__ flagp) {
    const int f32 = *flagp;
    int t = blockIdx.x * 256 + threadIdx.x;
    if (t < 4096) {
        const void* src = (t < 1024) ? bq : (t < 2048) ? bk : (t < 3072) ? bv : bo;
        int i = t & 1023;
        bias4[t] = f32 ? ((const float*)src)[i] : b2f(((const short*)src)[i]);
    } else if (t < 4096 + 65600) {
        int i = t - 4096;
        relb[i] = f32 ? f2b(((const float*)rel)[i]) : ((const short*)rel)[i];
    }
}

// ---------------------------------------------------------------------------
// Weight transpose: 4 x (1024,1024) (c,n) -> bf16 (n,c)
// ---------------------------------------------------------------------------
__global__ __launch_bounds__(256) void transpose4(
        const void* __restrict__ w0, const void* __restrict__ w1,
        const void* __restrict__ w2, const void* __restrict__ w3,
        short* __restrict__ dst, const int* __restrict__ flagp) {
    const int f32 = *flagp;
    __shared__ short tile[32][33];
    const void* src = (blockIdx.z == 0) ? w0 : (blockIdx.z == 1) ? w1
                    : (blockIdx.z == 2) ? w2 : w3;
    short* d = dst + (size_t)blockIdx.z * (D_MODEL * D_MODEL);
    int x = blockIdx.x * 32 + threadIdx.x;   // n
    int y0 = blockIdx.y * 32;                // c base
    for (int yy = threadIdx.y; yy < 32; yy += 8) {
        size_t idx = (size_t)(y0 + yy) * D_MODEL + x;
        tile[yy][threadIdx.x] = f32 ? f2b(((const float*)src)[idx])
                                    : ((const short*)src)[idx];
    }
    __syncthreads();
    int x0 = blockIdx.x * 32;
    for (int yy = threadIdx.y; yy < 32; yy += 8)
        d[(size_t)(x0 + yy) * D_MODEL + y0 + threadIdx.x] = tile[threadIdx.x][yy];
}

// ---------------------------------------------------------------------------
// Fused QKV projection GEMM (v4-proven staging): z = 0,1,2.
// C = A(4096,1024) @ WT^T + bias.  A fp32-or-bf16 per flag (VGPR staging,
// packed cvt). z 0/1 -> (b,h,l,d) bf16; z=2 -> (b,h,d,l) bf16 (V^T).
// 128x128 tile, BK=32, stride-40 LDS rows.
// ---------------------------------------------------------------------------
__global__ __launch_bounds__(256) void proj_gemm(
        const void* __restrict__ Aq, const void* __restrict__ Ak,
        const void* __restrict__ Av, const short* __restrict__ WT,
        const float* __restrict__ bias4, short* __restrict__ Qout,
        const int* __restrict__ flagp) {
    const int f32 = *flagp;
    const int z = blockIdx.z;
    const void* A_ = (z == 0) ? Aq : (z == 1) ? Ak : Av;
    const short* BT = WT + (size_t)z * (D_MODEL * D_MODEL);
    const float* bias = bias4 + z * 1024;
    short* C = Qout + (size_t)z * ((size_t)MROWS * D_MODEL);
    const int K = D_MODEL;

    __shared__ short Alds[128 * 40];
    __shared__ short Blds[128 * 40];
    const int tid = threadIdx.x;
    const int w = tid >> 6, lane = tid & 63, cl = lane & 15, quad = lane >> 4;
    const int wr = w >> 1, wc = w & 1;
    const int m0 = blockIdx.y * 128, n0 = blockIdx.x * 128;
    const int srow = tid >> 2, scol = (tid & 3) * 8;

    floatx4 acc[4][4];
    for (int i = 0; i < 4; i++)
        for (int j = 0; j < 4; j++)
            acc[i][j] = {0.f, 0.f, 0.f, 0.f};

    for (int k0 = 0; k0 < K; k0 += 32) {
        if (f32) {
            const float* Af = (const float*)A_;
            for (int half = 0; half < 2; half++) {
                size_t base = (size_t)(m0 + srow + half * 64) * K + k0 + scol;
                float4 f0 = *(const float4*)(&Af[base]);
                float4 f1 = *(const float4*)(&Af[base + 4]);
                uint4 s;
                s.x = pack2(f0.x, f0.y); s.y = pack2(f0.z, f0.w);
                s.z = pack2(f1.x, f1.y); s.w = pack2(f1.z, f1.w);
                *(uint4*)(&Alds[(srow + half * 64) * 40 + scol]) = s;
            }
        } else {
            const short* Ab = (const short*)A_;
            *(short8*)(&Alds[srow * 40 + scol]) =
                *(const short8*)(&Ab[(size_t)(m0 + srow) * K + k0 + scol]);
            *(short8*)(&Alds[(srow + 64) * 40 + scol]) =
                *(const short8*)(&Ab[(size_t)(m0 + srow + 64) * K + k0 + scol]);
        }
        *(short8*)(&Blds[srow * 40 + scol]) =
            *(const short8*)(&BT[(size_t)(n0 + srow) * K + k0 + scol]);
        *(short8*)(&Blds[(srow + 64) * 40 + scol]) =
            *(const short8*)(&BT[(size_t)(n0 + srow + 64) * K + k0 + scol]);
        __syncthreads();

        short8 af[4], bfr[4];
        for (int mt = 0; mt < 4; mt++)
            af[mt] = *(const short8*)(&Alds[(wr * 64 + mt * 16 + cl) * 40 + quad * 8]);
        for (int nt = 0; nt < 4; nt++)
            bfr[nt] = *(const short8*)(&Blds[(wc * 64 + nt * 16 + cl) * 40 + quad * 8]);
        for (int mt = 0; mt < 4; mt++)
            for (int nt = 0; nt < 4; nt++)
                acc[mt][nt] = __builtin_amdgcn_mfma_f32_16x16x32_bf16(
                    af[mt], bfr[nt], acc[mt][nt], 0, 0, 0);
        __syncthreads();
    }

    for (int nt = 0; nt < 4; nt++) {
        int n = n0 + wc * 64 + nt * 16 + cl;
        float bv = bias[n];
        int h = n >> 6, d = n & 63;
        for (int mt = 0; mt < 4; mt++) {
            for (int r = 0; r < 4; r++) {
                int m = m0 + wr * 64 + mt * 16 + quad * 4 + r;
                float v = acc[mt][nt][r] + bv;
                int b = m >> 11, i = m & 2047;
                if (z < 2)
                    C[(((size_t)(b * NHEAD + h)) * L_SEQ + i) * DH + d] = f2b(v);
                else
                    C[(((size_t)(b * NHEAD + h)) * DH + d) * L_SEQ + i] = f2b(v);
            }
        }
    }
}

// ---------------------------------------------------------------------------
// Output GEMM (v4-proven staging): C(4096,1024) = A @ WT^T + bias.
// 128x64 tile -> 512 blocks.
// ---------------------------------------------------------------------------
__global__ __launch_bounds__(256) void out_gemm(
        const short* __restrict__ A, const short* __restrict__ BT,
        const float* __restrict__ bias, void* __restrict__ C_,
        const int* __restrict__ flagp) {
    const int f32 = *flagp;
    const int K = D_MODEL, N = D_MODEL;
    __shared__ short Alds[128 * 40];
    __shared__ short Blds[64 * 40];
    const int tid = threadIdx.x;
    const int w = tid >> 6, lane = tid & 63, cl = lane & 15, quad = lane >> 4;
    const int wr = w >> 1, wc = w & 1;
    const int m0 = blockIdx.y * 128, n0 = blockIdx.x * 64;

    floatx4 acc[4][2];
    for (int i = 0; i < 4; i++)
        for (int j = 0; j < 2; j++)
            acc[i][j] = {0.f, 0.f, 0.f, 0.f};

    const int ar = tid >> 1, ac = (tid & 1) * 16;
    const int br = tid >> 2, bc = (tid & 3) * 8;

    for (int k0 = 0; k0 < K; k0 += 32) {
        *(short8*)(&Alds[ar * 40 + ac]) =
            *(const short8*)(&A[(size_t)(m0 + ar) * K + k0 + ac]);
        *(short8*)(&Alds[ar * 40 + ac + 8]) =
            *(const short8*)(&A[(size_t)(m0 + ar) * K + k0 + ac + 8]);
        *(short8*)(&Blds[br * 40 + bc]) =
            *(const short8*)(&BT[(size_t)(n0 + br) * K + k0 + bc]);
        __syncthreads();

        short8 af[4], bfr[2];
        for (int mt = 0; mt < 4; mt++)
            af[mt] = *(const short8*)(&Alds[(wr * 64 + mt * 16 + cl) * 40 + quad * 8]);
        for (int nt = 0; nt < 2; nt++)
            bfr[nt] = *(const short8*)(&Blds[(wc * 32 + nt * 16 + cl) * 40 + quad * 8]);
        for (int mt = 0; mt < 4; mt++)
            for (int nt = 0; nt < 2; nt++)
                acc[mt][nt] = __builtin_amdgcn_mfma_f32_16x16x32_bf16(
                    af[mt], bfr[nt], acc[mt][nt], 0, 0, 0);
        __syncthreads();
    }

    for (int nt = 0; nt < 2; nt++) {
        int n = n0 + wc * 32 + nt * 16 + cl;
        float bv = bias[n];
        for (int mt = 0; mt < 4; mt++) {
            for (int r = 0; r < 4; r++) {
                int m = m0 + wr * 64 + mt * 16 + quad * 4 + r;
                float v = acc[mt][nt][r] + bv;
                if (f32) ((float*)C_)[(size_t)m * N + n] = v;
                else     ((short*)C_)[(size_t)m * N + n] = f2b(v);
            }
        }
    }
}

// ---------------------------------------------------------------------------
// Flash attention (v5 structure, TBAA-safe LDS stores): transposed scores +
// fixed-shift softmax + banded pos. LDS 34.4 KB -> 4 blocks/CU.
// Pp bf16 [i][t] stride 86; epilogue transposes through Plds (reused).
// ---------------------------------------------------------------------------
__global__ __launch_bounds__(256) void attn_kernel(
        const short* __restrict__ Q, const short* __restrict__ K,
        const short* __restrict__ VT, const short* __restrict__ rel,
        short* __restrict__ out) {
    const int tid = threadIdx.x;
    const int w = tid >> 6, lane = tid & 63, cl = lane & 15, quad = lane >> 4;
    const int bh = blockIdx.y, b = bh >> 4, h = bh & 15;
    const int I0 = blockIdx.x * 64;
    const int iw0 = I0 + w * 16;

    const short* Qp = Q + (size_t)bh * L_SEQ * DH;
    const short* Kp = K + (size_t)bh * L_SEQ * DH;
    const short* Vp = VT + (size_t)bh * DH * L_SEQ;

    __shared__ short Klds[64 * 64];        // swizzled, 8KB
    __shared__ short Vtlds[64 * 64];       // swizzled, 8KB
    __shared__ short PpLds[4][16 * 86];    // per-wave pos [i][t], bf16, 10.75KB
    __shared__ short Plds[4][16 * 64];     // per-wave P, swizzled, 8KB

    short* PpW = &PpLds[w][0];
    short* PW  = &Plds[w][0];

    short8 aq[2];
    for (int c = 0; c < 2; c++)
        aq[c] = *(const short8*)(&Qp[(size_t)(iw0 + cl) * DH + c * 32 + quad * 8]);

    const float SCALE2 = 0.125f * 1.44269504088896340736f;  // /sqrt(64)*log2(e)
    const float FMAX = 32.0f;                               // fixed softmax shift

    // clamped-position row constants: q_i . E[0], q_i . E[1024]
    float addlo, addhi;
    {
        floatx4 Dc = {0.f, 0.f, 0.f, 0.f};
        int eidx = (cl == 1) ? 1024 : 0;
        for (int c = 0; c < 2; c++) {
            short8 ae = *(const short8*)(&rel[(size_t)eidx * DH + c * 32 + quad * 8]);
            Dc = __builtin_amdgcn_mfma_f32_16x16x32_bf16(ae, aq[c], Dc, 0, 0, 0);
        }
        float pcl = __shfl(Dc[0], cl, 64);
        float pch = __shfl(Dc[1], cl, 64);
        addlo = fmaf(pcl, SCALE2, -FMAX);
        addhi = fmaf(pch, SCALE2, -FMAX);
    }

    floatx4 O[4];
    for (int dt = 0; dt < 4; dt++) O[dt] = {0.f, 0.f, 0.f, 0.f};
    float lsum = 0.f;

    const int srow = tid >> 2;
    const int spair = (tid & 3) * 2;

    for (int j0 = 0; j0 < L_SEQ; j0 += 64) {
        for (int s = 0; s < 2; s++) {
            int chunk = spair + s;
            int pos = chunk ^ (srow & 7);
            *(short8*)(&Klds[srow * 64 + pos * 8]) =
                *(const short8*)(&Kp[(size_t)(j0 + srow) * DH + chunk * 8]);
            *(short8*)(&Vtlds[srow * 64 + pos * 8]) =
                *(const short8*)(&Vp[(size_t)srow * L_SEQ + j0 + chunk * 8]);
        }
        __syncthreads();

        const bool hi_clamp = (j0 - iw0 - 15) >= 512;
        const bool lo_clamp = (j0 + 63 - iw0) <= -512;
        const bool banded = !(hi_clamp || lo_clamp);
        const float addc = hi_clamp ? addhi : addlo;

        // --- content: S^T[j_loc][i] = K Q^T ---
        floatx4 St[4];
        for (int jt = 0; jt < 4; jt++) {
            St[jt] = {0.f, 0.f, 0.f, 0.f};
            int row = jt * 16 + cl;
            for (int c = 0; c < 2; c++) {
                int pos = ((4 * c + quad) ^ (cl & 7)) * 8;
                short8 bk = *(const short8*)(&Klds[row * 64 + pos]);
                St[jt] = __builtin_amdgcn_mfma_f32_16x16x32_bf16(bk, aq[c], St[jt], 0, 0, 0);
            }
        }

        if (banded) {
            // Pp^T[t][i], t window 0..78
            floatx4 Pt[5];
            for (int pt = 0; pt < 5; pt++) Pt[pt] = {0.f, 0.f, 0.f, 0.f};
            const int base = j0 - iw0 - 15;
            for (int pt = 0; pt < 5; pt++) {
                int raw = pt * 16 + cl + base;
                int idx = (raw < -512 ? -512 : (raw > 512 ? 512 : raw)) + 512;
                const short* ep = rel + (size_t)idx * DH;
                for (int c = 0; c < 2; c++) {
                    short8 be = *(const short8*)(&ep[c * 32 + quad * 8]);
                    Pt[pt] = __builtin_amdgcn_mfma_f32_16x16x32_bf16(be, aq[c], Pt[pt], 0, 0, 0);
                }
            }
            // store transposed [i=cl][t], packed pairs (t even) — ALIAS-SAFE
            for (int pt = 0; pt < 5; pt++) {
                int t = pt * 16 + quad * 4;
                st2(&PpW[cl * 86 + t],     pack2(Pt[pt][0], Pt[pt][1]));
                st2(&PpW[cl * 86 + t + 2], pack2(Pt[pt][2], Pt[pt][3]));
            }
            // wave-internal LDS RAW (memcpy stores may-alias -> ordered)
            for (int jt = 0; jt < 4; jt++)
                for (int r = 0; r < 4; r++) {
                    int t = jt * 16 + quad * 4 + r - cl + 15;   // 0..78
                    float pos = b2f(PpW[cl * 86 + t]);
                    St[jt][r] = fmaf(St[jt][r], SCALE2, fmaf(pos, SCALE2, -FMAX));
                }
        } else {
            for (int jt = 0; jt < 4; jt++)
                for (int r = 0; r < 4; r++)
                    St[jt][r] = fmaf(St[jt][r], SCALE2, addc);
        }

        // --- exp2 + sum ---
        for (int jt = 0; jt < 4; jt++)
            for (int r = 0; r < 4; r++) {
                float p = __builtin_amdgcn_exp2f(St[jt][r]);
                St[jt][r] = p;
                lsum += p;
            }

        // --- P -> per-wave LDS [i=cl][j_loc], swizzled, alias-safe b32 ---
        for (int jt = 0; jt < 4; jt++)
            for (int pr = 0; pr < 2; pr++) {
                int jl = jt * 16 + quad * 4 + pr * 2;
                int addr = cl * 64 + ((jl >> 3) ^ (cl & 7)) * 8 + (jl & 7);
                st2(&PW[addr], pack2(St[jt][2 * pr], St[jt][2 * pr + 1]));
            }

        // --- O^T += V^T P^T ---
        for (int c = 0; c < 2; c++) {
            int ppos = ((4 * c + quad) ^ (cl & 7)) * 8;
            short8 bp = *(const short8*)(&PW[cl * 64 + ppos]);
            for (int dt = 0; dt < 4; dt++) {
                int row = dt * 16 + cl;
                int vpos = ((4 * c + quad) ^ (cl & 7)) * 8;
                short8 av = *(const short8*)(&Vtlds[row * 64 + vpos]);
                O[dt] = __builtin_amdgcn_mfma_f32_16x16x32_bf16(av, bp, O[dt], 0, 0, 0);
            }
        }
        __syncthreads();   // before next staging overwrites K/V tiles
    }

    // --- l reduction (once) ---
    lsum += __shfl_xor(lsum, 16, 64);
    lsum += __shfl_xor(lsum, 32, 64);
    float inv = 1.0f / lsum;

    // --- epilogue: O^T*inv -> bf16 transpose via PW (reused, alias-safe) ---
    for (int dt = 0; dt < 4; dt++)
        for (int pr = 0; pr < 2; pr++) {
            int jl = dt * 16 + quad * 4 + pr * 2;   // d index
            int addr = cl * 64 + ((jl >> 3) ^ (cl & 7)) * 8 + (jl & 7);
            st2(&PW[addr], pack2(O[dt][2 * pr] * inv, O[dt][2 * pr + 1] * inv));
        }
    // wave-internal; memcpy stores ordered vs short8 reads
    size_t obase = ((size_t)b * L_SEQ + iw0 + cl) * D_MODEL + h * DH;
    for (int s = 0; s < 2; s++) {
        int c2 = quad * 2 + s;
        short8 o = *(const short8*)(&PW[cl * 64 + (c2 ^ (cl & 7)) * 8]);
        *(short8*)(&out[obase + c2 * 8]) = o;
    }
}

// ---------------------------------------------------------------------------
extern "C" void kernel_launch(void* const* d_in, const int* in_sizes, int n_in,
                              void* d_out, int out_size, void* d_ws, size_t ws_size,
                              hipStream_t stream) {
    const void* query = d_in[0];
    const void* key   = d_in[1];
    const void* value = d_in[2];
    const void* wq = d_in[3];  const void* bq = d_in[4];
    const void* wk = d_in[5];  const void* bk = d_in[6];
    const void* wv = d_in[7];  const void* bv = d_in[8];
    const void* wo = d_in[9];  const void* bo = d_in[10];
    const void* rel = d_in[11];

    // v4-proven 40.2MB layout.
    int* flag = (int*)d_ws;
    short* ws = (short*)d_ws + 16;                     // 32B offset
    const size_t WSZ = (size_t)D_MODEL * D_MODEL;      // 1M elems per weight
    const size_t TSZ = (size_t)MROWS * D_MODEL;        // 4M elems per tensor
    short* WT   = ws;                                  // 4 x WSZ (q,k,v,o)
    short* Qw   = ws + 4 * WSZ;
    short* Kw   = Qw + TSZ;
    short* Vtw  = Kw + TSZ;
    short* Attw = Vtw + TSZ;
    float* bias4 = (float*)(Attw + TSZ);               // 4096 fp32
    short* relb  = (short*)(bias4 + 4096);             // 65600 bf16

    detect_dtype<<<1, 256, 0, stream>>>((const unsigned short*)query, flag);
    norm_small<<<273, 256, 0, stream>>>(bq, bk, bv, bo, rel, bias4, relb, flag);
    transpose4<<<dim3(32, 32, 4), dim3(32, 8), 0, stream>>>(wq, wk, wv, wo, WT, flag);

    proj_gemm<<<dim3(8, 32, 3), 256, 0, stream>>>(query, key, value, WT, bias4,
                                                  Qw, flag);

    attn_kernel<<<dim3(L_SEQ / 64, BH), 256, 0, stream>>>(Qw, Kw, Vtw, relb, Attw);

    out_gemm<<<dim3(16, 32), 256, 0, stream>>>(Attw, WT + 3 * WSZ, bias4 + 3072,
                                               d_out, flag);
}

// Round 9
// 383.588 us; speedup vs baseline: 1.0331x; 1.0331x over previous
//
#include <hip/hip_runtime.h>
#include <hip/hip_bf16.h>

// ---------------------------------------------------------------------------
// RelativeMultiHeadAttention: B=2, L=2048, D=1024, H=16, d=64, MAX_REL=512
// Inputs fp32 (auto-detected vs bf16). Internals bf16 MFMA + fp32 accum.
//
// v9: v8 + async GEMM staging (global_load_lds width=16, m97 layout).
// v5-v7 NaN root cause was attn's scalar-TBAA LDS pun (fixed in v8 via
// memcpy st2); async was never implicated (v7 NaN'd with zero async).
// GEMM LDS rows stride 32 (lane-linear for DMA); A-fp32 path keeps the
// proven pack2 VGPR staging. attn byte-identical to v8 (passed, 139us).
// ---------------------------------------------------------------------------

typedef __attribute__((ext_vector_type(8))) short short8;   // 8 x bf16 frag
typedef __attribute__((ext_vector_type(4))) float floatx4;

#define L_SEQ 2048
#define D_MODEL 1024
#define NHEAD 16
#define DH 64
#define BH 32           // B*H
#define MROWS 4096      // B*L

__device__ inline float b2f(short s) {
    unsigned int u = ((unsigned int)(unsigned short)s) << 16;
    float f; __builtin_memcpy(&f, &u, 4); return f;
}
__device__ inline short f2b(float f) {
    unsigned int u; __builtin_memcpy(&u, &f, 4);
    u += 0x7fffu + ((u >> 16) & 1u);   // round-to-nearest-even
    return (short)(u >> 16);
}
// packed f32x2 -> bf16x2 (v_cvt_pk_bf16_f32 on gfx950)
__device__ inline unsigned int pack2(float a, float b) {
    __hip_bfloat162 h = __float22bfloat162_rn(make_float2(a, b));
    unsigned int u; __builtin_memcpy(&u, &h, 4); return u;
}
// alias-safe 4B store into a short-typed LDS array (ds_write_b32)
__device__ inline void st2(short* p, unsigned int v) {
    __builtin_memcpy(p, &v, 4);
}
// async global->LDS, 16B per lane; lds base must be wave-uniform
__device__ inline void async_cp16(short* lds, const short* g) {
    __builtin_amdgcn_global_load_lds(
        (const __attribute__((address_space(1))) unsigned int*)g,
        (__attribute__((address_space(3))) unsigned int*)lds, 16, 0, 0);
}

// ---------------------------------------------------------------------------
// dtype detector: count bf16 inf/nan exponent patterns in first 64K shorts.
// ---------------------------------------------------------------------------
__global__ __launch_bounds__(256) void detect_dtype(
        const unsigned short* __restrict__ q, int* __restrict__ flag) {
    __shared__ int s[256];
    int tid = threadIdx.x, cnt = 0;
    for (int i = tid; i < 65536; i += 256)
        if ((q[i] & 0x7F80u) == 0x7F80u) cnt++;
    s[tid] = cnt; __syncthreads();
    for (int st = 128; st; st >>= 1) {
        if (tid < st) s[tid] += s[tid + st];
        __syncthreads();
    }
    if (tid == 0) *flag = (s[0] > 4) ? 1 : 0;   // 1 = inputs are fp32
}

// ---------------------------------------------------------------------------
// Canonicalize small tensors: 4 biases -> fp32[4096], rel_emb -> bf16[65600]
// ---------------------------------------------------------------------------
__global__ __launch_bounds__(256) void norm_small(
        const void* __restrict__ bq, const void* __restrict__ bk,
        const void* __restrict__ bv, const void* __restrict__ bo,
        const void* __restrict__ rel, float* __restrict__ bias4,
        short* __restrict__ relb, const int* __restrict__ flagp) {
    const int f32 = *flagp;
    int t = blockIdx.x * 256 + threadIdx.x;
    if (t < 4096) {
        const void* src = (t < 1024) ? bq : (t < 2048) ? bk : (t < 3072) ? bv : bo;
        int i = t & 1023;
        bias4[t] = f32 ? ((const float*)src)[i] : b2f(((const short*)src)[i]);
    } else if (t < 4096 + 65600) {
        int i = t - 4096;
        relb[i] = f32 ? f2b(((const float*)rel)[i]) : ((const short*)rel)[i];
    }
}

// ---------------------------------------------------------------------------
// Weight transpose: 4 x (1024,1024) (c,n) -> bf16 (n,c)
// ---------------------------------------------------------------------------
__global__ __launch_bounds__(256) void transpose4(
        const void* __restrict__ w0, const void* __restrict__ w1,
        const void* __restrict__ w2, const void* __restrict__ w3,
        short* __restrict__ dst, const int* __restrict__ flagp) {
    const int f32 = *flagp;
    __shared__ short tile[32][33];
    const void* src = (blockIdx.z == 0) ? w0 : (blockIdx.z == 1) ? w1
                    : (blockIdx.z == 2) ? w2 : w3;
    short* d = dst + (size_t)blockIdx.z * (D_MODEL * D_MODEL);
    int x = blockIdx.x * 32 + threadIdx.x;   // n
    int y0 = blockIdx.y * 32;                // c base
    for (int yy = threadIdx.y; yy < 32; yy += 8) {
        size_t idx = (size_t)(y0 + yy) * D_MODEL + x;
        tile[yy][threadIdx.x] = f32 ? f2b(((const float*)src)[idx])
                                    : ((const short*)src)[idx];
    }
    __syncthreads();
    int x0 = blockIdx.x * 32;
    for (int yy = threadIdx.y; yy < 32; yy += 8)
        d[(size_t)(x0 + yy) * D_MODEL + y0 + threadIdx.x] = tile[threadIdx.x][yy];
}

// ---------------------------------------------------------------------------
// Fused QKV projection GEMM: z = 0,1,2.  C = A(4096,1024) @ WT^T + bias.
// B (bf16) via global_load_lds width 16 (m97 layout, stride-32 rows).
// A: bf16 -> async; fp32 -> VGPR pack2 staging (proven).
// z 0/1 -> (b,h,l,d) bf16; z=2 -> (b,h,d,l) bf16 (V^T).
// ---------------------------------------------------------------------------
__global__ __launch_bounds__(256) void proj_gemm(
        const void* __restrict__ Aq, const void* __restrict__ Ak,
        const void* __restrict__ Av, const short* __restrict__ WT,
        const float* __restrict__ bias4, short* __restrict__ Qout,
        const int* __restrict__ flagp) {
    const int f32 = *flagp;
    const int z = blockIdx.z;
    const void* A_ = (z == 0) ? Aq : (z == 1) ? Ak : Av;
    const short* BT = WT + (size_t)z * (D_MODEL * D_MODEL);
    const float* bias = bias4 + z * 1024;
    short* C = Qout + (size_t)z * ((size_t)MROWS * D_MODEL);
    const int K = D_MODEL;

    __shared__ short Alds[128 * 32];
    __shared__ short Blds[128 * 32];
    const int tid = threadIdx.x;
    const int w = tid >> 6, lane = tid & 63, cl = lane & 15, quad = lane >> 4;
    const int wr = w >> 1, wc = w & 1;
    const int m0 = blockIdx.y * 128, n0 = blockIdx.x * 128;
    const int srow = tid >> 2, scol = (tid & 3) * 8;     // VGPR staging map
    const int grow = lane >> 2, gcol = (lane & 3) * 8;   // async staging map

    floatx4 acc[4][4];
    for (int i = 0; i < 4; i++)
        for (int j = 0; j < 4; j++)
            acc[i][j] = {0.f, 0.f, 0.f, 0.f};

    for (int k0 = 0; k0 < K; k0 += 32) {
        // B: always bf16 -> async direct-to-LDS (wave-uniform base+lane*16B)
        for (int s = 0; s < 2; s++) {
            int r = w * 32 + s * 16;
            async_cp16(&Blds[r * 32], &BT[(size_t)(n0 + r + grow) * K + k0 + gcol]);
        }
        if (f32) {
            const float* Af = (const float*)A_;
            for (int half = 0; half < 2; half++) {
                size_t base = (size_t)(m0 + srow + half * 64) * K + k0 + scol;
                float4 f0 = *(const float4*)(&Af[base]);
                float4 f1 = *(const float4*)(&Af[base + 4]);
                uint4 s;
                s.x = pack2(f0.x, f0.y); s.y = pack2(f0.z, f0.w);
                s.z = pack2(f1.x, f1.y); s.w = pack2(f1.z, f1.w);
                *(uint4*)(&Alds[(srow + half * 64) * 32 + scol]) = s;
            }
        } else {
            const short* Ab = (const short*)A_;
            for (int s = 0; s < 2; s++) {
                int r = w * 32 + s * 16;
                async_cp16(&Alds[r * 32], &Ab[(size_t)(m0 + r + grow) * K + k0 + gcol]);
            }
        }
        __syncthreads();

        short8 af[4], bfr[4];
        for (int mt = 0; mt < 4; mt++)
            af[mt] = *(const short8*)(&Alds[(wr * 64 + mt * 16 + cl) * 32 + quad * 8]);
        for (int nt = 0; nt < 4; nt++)
            bfr[nt] = *(const short8*)(&Blds[(wc * 64 + nt * 16 + cl) * 32 + quad * 8]);
        for (int mt = 0; mt < 4; mt++)
            for (int nt = 0; nt < 4; nt++)
                acc[mt][nt] = __builtin_amdgcn_mfma_f32_16x16x32_bf16(
                    af[mt], bfr[nt], acc[mt][nt], 0, 0, 0);
        __syncthreads();
    }

    for (int nt = 0; nt < 4; nt++) {
        int n = n0 + wc * 64 + nt * 16 + cl;
        float bv = bias[n];
        int h = n >> 6, d = n & 63;
        for (int mt = 0; mt < 4; mt++) {
            for (int r = 0; r < 4; r++) {
                int m = m0 + wr * 64 + mt * 16 + quad * 4 + r;
                float v = acc[mt][nt][r] + bv;
                int b = m >> 11, i = m & 2047;
                if (z < 2)
                    C[(((size_t)(b * NHEAD + h)) * L_SEQ + i) * DH + d] = f2b(v);
                else
                    C[(((size_t)(b * NHEAD + h)) * DH + d) * L_SEQ + i] = f2b(v);
            }
        }
    }
}

// ---------------------------------------------------------------------------
// Output GEMM: C(4096,1024) = A @ WT^T + bias.  128x64 tile, full async.
// ---------------------------------------------------------------------------
__global__ __launch_bounds__(256) void out_gemm(
        const short* __restrict__ A, const short* __restrict__ BT,
        const float* __restrict__ bias, void* __restrict__ C_,
        const int* __restrict__ flagp) {
    const int f32 = *flagp;
    const int K = D_MODEL, N = D_MODEL;
    __shared__ short Alds[128 * 32];
    __shared__ short Blds[64 * 32];
    const int tid = threadIdx.x;
    const int w = tid >> 6, lane = tid & 63, cl = lane & 15, quad = lane >> 4;
    const int wr = w >> 1, wc = w & 1;
    const int m0 = blockIdx.y * 128, n0 = blockIdx.x * 64;
    const int grow = lane >> 2, gcol = (lane & 3) * 8;

    floatx4 acc[4][2];
    for (int i = 0; i < 4; i++)
        for (int j = 0; j < 2; j++)
            acc[i][j] = {0.f, 0.f, 0.f, 0.f};

    for (int k0 = 0; k0 < K; k0 += 32) {
        for (int s = 0; s < 2; s++) {
            int r = w * 32 + s * 16;
            async_cp16(&Alds[r * 32], &A[(size_t)(m0 + r + grow) * K + k0 + gcol]);
        }
        {
            int r = w * 16;
            async_cp16(&Blds[r * 32], &BT[(size_t)(n0 + r + grow) * K + k0 + gcol]);
        }
        __syncthreads();

        short8 af[4], bfr[2];
        for (int mt = 0; mt < 4; mt++)
            af[mt] = *(const short8*)(&Alds[(wr * 64 + mt * 16 + cl) * 32 + quad * 8]);
        for (int nt = 0; nt < 2; nt++)
            bfr[nt] = *(const short8*)(&Blds[(wc * 32 + nt * 16 + cl) * 32 + quad * 8]);
        for (int mt = 0; mt < 4; mt++)
            for (int nt = 0; nt < 2; nt++)
                acc[mt][nt] = __builtin_amdgcn_mfma_f32_16x16x32_bf16(
                    af[mt], bfr[nt], acc[mt][nt], 0, 0, 0);
        __syncthreads();
    }

    for (int nt = 0; nt < 2; nt++) {
        int n = n0 + wc * 32 + nt * 16 + cl;
        float bv = bias[n];
        for (int mt = 0; mt < 4; mt++) {
            for (int r = 0; r < 4; r++) {
                int m = m0 + wr * 64 + mt * 16 + quad * 4 + r;
                float v = acc[mt][nt][r] + bv;
                if (f32) ((float*)C_)[(size_t)m * N + n] = v;
                else     ((short*)C_)[(size_t)m * N + n] = f2b(v);
            }
        }
    }
}

// ---------------------------------------------------------------------------
// Flash attention (v8, byte-identical): transposed scores + fixed-shift
// softmax + banded pos. TBAA-safe LDS stores (st2/memcpy). 34.4 KB LDS.
// ---------------------------------------------------------------------------
__global__ __launch_bounds__(256) void attn_kernel(
        const short* __restrict__ Q, const short* __restrict__ K,
        const short* __restrict__ VT, const short* __restrict__ rel,
        short* __restrict__ out) {
    const int tid = threadIdx.x;
    const int w = tid >> 6, lane = tid & 63, cl = lane & 15, quad = lane >> 4;
    const int bh = blockIdx.y, b = bh >> 4, h = bh & 15;
    const int I0 = blockIdx.x * 64;
    const int iw0 = I0 + w * 16;

    const short* Qp = Q + (size_t)bh * L_SEQ * DH;
    const short* Kp = K + (size_t)bh * L_SEQ * DH;
    const short* Vp = VT + (size_t)bh * DH * L_SEQ;

    __shared__ short Klds[64 * 64];        // swizzled, 8KB
    __shared__ short Vtlds[64 * 64];       // swizzled, 8KB
    __shared__ short PpLds[4][16 * 86];    // per-wave pos [i][t], bf16, 10.75KB
    __shared__ short Plds[4][16 * 64];     // per-wave P, swizzled, 8KB

    short* PpW = &PpLds[w][0];
    short* PW  = &Plds[w][0];

    short8 aq[2];
    for (int c = 0; c < 2; c++)
        aq[c] = *(const short8*)(&Qp[(size_t)(iw0 + cl) * DH + c * 32 + quad * 8]);

    const float SCALE2 = 0.125f * 1.44269504088896340736f;  // /sqrt(64)*log2(e)
    const float FMAX = 32.0f;                               // fixed softmax shift

    // clamped-position row constants: q_i . E[0], q_i . E[1024]
    float addlo, addhi;
    {
        floatx4 Dc = {0.f, 0.f, 0.f, 0.f};
        int eidx = (cl == 1) ? 1024 : 0;
        for (int c = 0; c < 2; c++) {
            short8 ae = *(const short8*)(&rel[(size_t)eidx * DH + c * 32 + quad * 8]);
            Dc = __builtin_amdgcn_mfma_f32_16x16x32_bf16(ae, aq[c], Dc, 0, 0, 0);
        }
        float pcl = __shfl(Dc[0], cl, 64);
        float pch = __shfl(Dc[1], cl, 64);
        addlo = fmaf(pcl, SCALE2, -FMAX);
        addhi = fmaf(pch, SCALE2, -FMAX);
    }

    floatx4 O[4];
    for (int dt = 0; dt < 4; dt++) O[dt] = {0.f, 0.f, 0.f, 0.f};
    float lsum = 0.f;

    const int srow = tid >> 2;
    const int spair = (tid & 3) * 2;

    for (int j0 = 0; j0 < L_SEQ; j0 += 64) {
        for (int s = 0; s < 2; s++) {
            int chunk = spair + s;
            int pos = chunk ^ (srow & 7);
            *(short8*)(&Klds[srow * 64 + pos * 8]) =
                *(const short8*)(&Kp[(size_t)(j0 + srow) * DH + chunk * 8]);
            *(short8*)(&Vtlds[srow * 64 + pos * 8]) =
                *(const short8*)(&Vp[(size_t)srow * L_SEQ + j0 + chunk * 8]);
        }
        __syncthreads();

        const bool hi_clamp = (j0 - iw0 - 15) >= 512;
        const bool lo_clamp = (j0 + 63 - iw0) <= -512;
        const bool banded = !(hi_clamp || lo_clamp);
        const float addc = hi_clamp ? addhi : addlo;

        // --- content: S^T[j_loc][i] = K Q^T ---
        floatx4 St[4];
        for (int jt = 0; jt < 4; jt++) {
            St[jt] = {0.f, 0.f, 0.f, 0.f};
            int row = jt * 16 + cl;
            for (int c = 0; c < 2; c++) {
                int pos = ((4 * c + quad) ^ (cl & 7)) * 8;
                short8 bk = *(const short8*)(&Klds[row * 64 + pos]);
                St[jt] = __builtin_amdgcn_mfma_f32_16x16x32_bf16(bk, aq[c], St[jt], 0, 0, 0);
            }
        }

        if (banded) {
            // Pp^T[t][i], t window 0..78
            floatx4 Pt[5];
            for (int pt = 0; pt < 5; pt++) Pt[pt] = {0.f, 0.f, 0.f, 0.f};
            const int base = j0 - iw0 - 15;
            for (int pt = 0; pt < 5; pt++) {
                int raw = pt * 16 + cl + base;
                int idx = (raw < -512 ? -512 : (raw > 512 ? 512 : raw)) + 512;
                const short* ep = rel + (size_t)idx * DH;
                for (int c = 0; c < 2; c++) {
                    short8 be = *(const short8*)(&ep[c * 32 + quad * 8]);
                    Pt[pt] = __builtin_amdgcn_mfma_f32_16x16x32_bf16(be, aq[c], Pt[pt], 0, 0, 0);
                }
            }
            // store transposed [i=cl][t], packed pairs (t even) — alias-safe
            for (int pt = 0; pt < 5; pt++) {
                int t = pt * 16 + quad * 4;
                st2(&PpW[cl * 86 + t],     pack2(Pt[pt][0], Pt[pt][1]));
                st2(&PpW[cl * 86 + t + 2], pack2(Pt[pt][2], Pt[pt][3]));
            }
            // wave-internal LDS RAW (memcpy stores may-alias -> ordered)
            for (int jt = 0; jt < 4; jt++)
                for (int r = 0; r < 4; r++) {
                    int t = jt * 16 + quad * 4 + r - cl + 15;   // 0..78
                    float pos = b2f(PpW[cl * 86 + t]);
                    St[jt][r] = fmaf(St[jt][r], SCALE2, fmaf(pos, SCALE2, -FMAX));
                }
        } else {
            for (int jt = 0; jt < 4; jt++)
                for (int r = 0; r < 4; r++)
                    St[jt][r] = fmaf(St[jt][r], SCALE2, addc);
        }

        // --- exp2 + sum ---
        for (int jt = 0; jt < 4; jt++)
            for (int r = 0; r < 4; r++) {
                float p = __builtin_amdgcn_exp2f(St[jt][r]);
                St[jt][r] = p;
                lsum += p;
            }

        // --- P -> per-wave LDS [i=cl][j_loc], swizzled, alias-safe b32 ---
        for (int jt = 0; jt < 4; jt++)
            for (int pr = 0; pr < 2; pr++) {
                int jl = jt * 16 + quad * 4 + pr * 2;
                int addr = cl * 64 + ((jl >> 3) ^ (cl & 7)) * 8 + (jl & 7);
                st2(&PW[addr], pack2(St[jt][2 * pr], St[jt][2 * pr + 1]));
            }

        // --- O^T += V^T P^T ---
        for (int c = 0; c < 2; c++) {
            int ppos = ((4 * c + quad) ^ (cl & 7)) * 8;
            short8 bp = *(const short8*)(&PW[cl * 64 + ppos]);
            for (int dt = 0; dt < 4; dt++) {
                int row = dt * 16 + cl;
                int vpos = ((4 * c + quad) ^ (cl & 7)) * 8;
                short8 av = *(const short8*)(&Vtlds[row * 64 + vpos]);
                O[dt] = __builtin_amdgcn_mfma_f32_16x16x32_bf16(av, bp, O[dt], 0, 0, 0);
            }
        }
        __syncthreads();   // before next staging overwrites K/V tiles
    }

    // --- l reduction (once) ---
    lsum += __shfl_xor(lsum, 16, 64);
    lsum += __shfl_xor(lsum, 32, 64);
    float inv = 1.0f / lsum;

    // --- epilogue: O^T*inv -> bf16 transpose via PW (reused, alias-safe) ---
    for (int dt = 0; dt < 4; dt++)
        for (int pr = 0; pr < 2; pr++) {
            int jl = dt * 16 + quad * 4 + pr * 2;   // d index
            int addr = cl * 64 + ((jl >> 3) ^ (cl & 7)) * 8 + (jl & 7);
            st2(&PW[addr], pack2(O[dt][2 * pr] * inv, O[dt][2 * pr + 1] * inv));
        }
    // wave-internal; memcpy stores ordered vs short8 reads
    size_t obase = ((size_t)b * L_SEQ + iw0 + cl) * D_MODEL + h * DH;
    for (int s = 0; s < 2; s++) {
        int c2 = quad * 2 + s;
        short8 o = *(const short8*)(&PW[cl * 64 + (c2 ^ (cl & 7)) * 8]);
        *(short8*)(&out[obase + c2 * 8]) = o;
    }
}

// ---------------------------------------------------------------------------
extern "C" void kernel_launch(void* const* d_in, const int* in_sizes, int n_in,
                              void* d_out, int out_size, void* d_ws, size_t ws_size,
                              hipStream_t stream) {
    const void* query = d_in[0];
    const void* key   = d_in[1];
    const void* value = d_in[2];
    const void* wq = d_in[3];  const void* bq = d_in[4];
    const void* wk = d_in[5];  const void* bk = d_in[6];
    const void* wv = d_in[7];  const void* bv = d_in[8];
    const void* wo = d_in[9];  const void* bo = d_in[10];
    const void* rel = d_in[11];

    // v4-proven 40.2MB layout.
    int* flag = (int*)d_ws;
    short* ws = (short*)d_ws + 16;                     // 32B offset
    const size_t WSZ = (size_t)D_MODEL * D_MODEL;      // 1M elems per weight
    const size_t TSZ = (size_t)MROWS * D_MODEL;        // 4M elems per tensor
    short* WT   = ws;                                  // 4 x WSZ (q,k,v,o)
    short* Qw   = ws + 4 * WSZ;
    short* Kw   = Qw + TSZ;
    short* Vtw  = Kw + TSZ;
    short* Attw = Vtw + TSZ;
    float* bias4 = (float*)(Attw + TSZ);               // 4096 fp32
    short* relb  = (short*)(bias4 + 4096);             // 65600 bf16

    detect_dtype<<<1, 256, 0, stream>>>((const unsigned short*)query, flag);
    norm_small<<<273, 256, 0, stream>>>(bq, bk, bv, bo, rel, bias4, relb, flag);
    transpose4<<<dim3(32, 32, 4), dim3(32, 8), 0, stream>>>(wq, wk, wv, wo, WT, flag);

    proj_gemm<<<dim3(8, 32, 3), 256, 0, stream>>>(query, key, value, WT, bias4,
                                                  Qw, flag);

    attn_kernel<<<dim3(L_SEQ / 64, BH), 256, 0, stream>>>(Qw, Kw, Vtw, relb, Attw);

    out_gemm<<<dim3(16, 32), 256, 0, stream>>>(Attw, WT + 3 * WSZ, bias4 + 3072,
                                               d_out, flag);
}